// Round 5
// baseline (588.299 us; speedup 1.0000x reference)
//
#include <hip/hip_runtime.h>
#include <math.h>

#define B_ 8192
#define H_ 1024
#define K2 2048

typedef __attribute__((ext_vector_type(8))) short bf16x8;
typedef __attribute__((ext_vector_type(4))) float f32x4;
typedef unsigned short u16;

__device__ __forceinline__ u16 f2bf(float f) {
  unsigned u = __float_as_uint(f);
  u += 0x7fffu + ((u >> 16) & 1u);  // round-to-nearest-even
  return (u16)(u >> 16);
}
__device__ __forceinline__ float bf2f(u16 s) { return __uint_as_float(((unsigned)s) << 16); }

// ---- split fp32 [B][1024] into hi/lo bf16 written into [B][2048] at column offset ----
__global__ __launch_bounds__(256) void split_hl(const float* __restrict__ src,
                                                u16* __restrict__ hi, u16* __restrict__ lo,
                                                int col04) {
  const int n4 = B_ * H_ / 4;
  int i = blockIdx.x * blockDim.x + threadIdx.x;
  int stride = gridDim.x * blockDim.x;
  for (; i < n4; i += stride) {
    float4 v = reinterpret_cast<const float4*>(src)[i];
    int row = i >> 8;  // 256 float4 per source row
    int c4 = i & 255;
    float c[4] = {v.x, v.y, v.z, v.w};
    u16 hh[4], ll[4];
#pragma unroll
    for (int j = 0; j < 4; j++) {
      hh[j] = f2bf(c[j]);
      ll[j] = f2bf(c[j] - bf2f(hh[j]));
    }
    ushort4 h4 = {hh[0], hh[1], hh[2], hh[3]};
    ushort4 l4 = {ll[0], ll[1], ll[2], ll[3]};
    size_t o4 = (size_t)row * (K2 / 4) + col04 + c4;
    reinterpret_cast<ushort4*>(hi)[o4] = h4;
    reinterpret_cast<ushort4*>(lo)[o4] = l4;
  }
}

// ---- W[K][N] -> T[N][ldo] (K-major) with hi/lo split, at column offset koff ----
__global__ __launch_bounds__(256) void transpose_split(const float* __restrict__ W,
                                                       u16* __restrict__ Thi,
                                                       u16* __restrict__ Tlo,
                                                       int K, int N, int ldo, int koff) {
  __shared__ float tile[32][33];
  int bx = blockIdx.x * 32;  // N offset
  int by = blockIdx.y * 32;  // K offset
  int tx = threadIdx.x, ty = threadIdx.y;  // 32 x 8
#pragma unroll
  for (int i = 0; i < 4; i++)
    tile[ty + i * 8][tx] = W[(size_t)(by + ty + i * 8) * N + bx + tx];
  __syncthreads();
#pragma unroll
  for (int i = 0; i < 4; i++) {
    float v = tile[tx][ty + i * 8];  // = W[by+tx][bx+ty+i*8]
    u16 hv = f2bf(v);
    u16 lv = f2bf(v - bf2f(hv));
    size_t o = (size_t)(bx + ty + i * 8) * ldo + koff + by + tx;
    Thi[o] = hv;
    Tlo[o] = lv;
  }
}

// ---- bf16x3 MFMA GEMM: C = Ahi/lo[M][K](lda) * (Bhi/lo[N][K])^T + bias[N] ----
// mode 0: plain.  mode 1: fused GRU gate epilogue (acc is r-preact w/o bias).
// T3+T4 pipeline: double-buffered LDS, 2-deep prefetch, counted vmcnt(8) in
// the main loop (never drains to 0), raw s_barriers, T5 setprio around MFMA.
#define BM 128
#define BN 128
#define BK 32

__device__ __forceinline__ void gload16(const void* g, void* l) {
  __builtin_amdgcn_global_load_lds((const __attribute__((address_space(1))) unsigned int*)g,
                                   (__attribute__((address_space(3))) unsigned int*)l,
                                   16, 0, 0);
}

__global__ __launch_bounds__(256, 2) void gemm3(const u16* __restrict__ Ahi,
                                                const u16* __restrict__ Alo, int lda,
                                                const u16* __restrict__ Bhi,
                                                const u16* __restrict__ Blo,
                                                const float* __restrict__ bias, float* C,
                                                int N, int K, int mode,
                                                const float* zbuf, const float* xnbuf,
                                                const float* hnbuf, const float* hbuf) {
  // LDS: [buf][A/B][row 0..127][granule 0..7][8 elems].  granule g of row r
  // holds logical (seg,hl) with 2*seg+hl = g ^ (r&7)  (seg = k-octet, hl =
  // hi/lo plane).  Involution applied on BOTH the pre-swizzled global source
  // (stage) and the ds_read offsets (rule #21).  Row stride 128 B -> per
  // ds_read_b128 each 4-bank window serves 8 lanes = the volume floor (the
  // geometry that measured SQ_LDS_BANK_CONFLICT == 0 in round 4).
  __shared__ u16 lds[2][2 * BM * 2 * BK];  // 2 x 32 KiB

  const int tid = threadIdx.x;
  const int lane = tid & 63;
  const int wv = tid >> 6;
  const int wr = wv >> 1, wc = wv & 1;  // 2x2 waves, 64x64 tile each
  const int fr = lane & 15;
  const int fs = lane >> 4;

  // T1: bijective XCD chunk swizzle (nwg = 512, %8 == 0).
  const int lin = blockIdx.y * gridDim.x + blockIdx.x;
  const int cpx = (gridDim.x * gridDim.y) >> 3;
  const int nlin = (lin & 7) * cpx + (lin >> 3);
  const int m0 = (nlin / gridDim.x) * BM;
  const int n0 = (nlin % gridDim.x) * BN;

  // Per-thread staging descriptors: 8 granule-slots/thread/K-step.
  // gp[q] advances by BK each stage; LDS dest is wave-uniform base + lane*16.
  const u16* gp[8];
  int ldsoff[8];
#pragma unroll
  for (int q = 0; q < 8; q++) {
    int idx = q * 256 + tid;          // 0..2047: [A/B][row][granule]
    int isB = idx >> 10;
    int r = (idx >> 3) & 127;
    int l = (idx & 7) ^ (r & 7);      // logical granule
    int seg = l >> 1, hl = l & 1;
    const u16* hiP = isB ? Bhi : Ahi;
    const u16* loP = isB ? Blo : Alo;
    size_t row_ld = isB ? (size_t)K : (size_t)lda;
    int row0 = isB ? n0 : m0;
    gp[q] = (hl ? loP : hiP) + (size_t)(row0 + r) * row_ld + seg * 8;
    ldsoff[q] = idx * 8;              // elems; linear LDS (gload_lds requirement)
  }

  // Frag ds_read offsets (elems), static per thread.
  int oah[4], oal[4], obh[4], obl[4];
#pragma unroll
  for (int i = 0; i < 4; i++) {
    int ar = wr * 64 + i * 16 + fr;
    oah[i] = ar * 64 + ((((fs << 1)) ^ (ar & 7)) << 3);
    oal[i] = ar * 64 + ((((fs << 1) | 1) ^ (ar & 7)) << 3);
    int br = wc * 64 + i * 16 + fr;
    obh[i] = 2 * BM * BK + br * 64 + ((((fs << 1)) ^ (br & 7)) << 3);
    obl[i] = 2 * BM * BK + br * 64 + ((((fs << 1) | 1) ^ (br & 7)) << 3);
  }

  f32x4 acc[4][4] = {};
  const int nt = K / BK;

  auto stage = [&](int b) {
#pragma unroll
    for (int q = 0; q < 8; q++) {
      gload16(gp[q], &lds[b][0] + ldsoff[q]);
      gp[q] += BK;
    }
  };

  // Prologue: tiles 0 and 1 in flight; wait only for tile 0.
  stage(0);
  stage(1);
  asm volatile("s_waitcnt vmcnt(8)" ::: "memory");
  __builtin_amdgcn_sched_barrier(0);
  __builtin_amdgcn_s_barrier();

  for (int t = 0; t < nt; ++t) {
    const int b = t & 1;
    const u16* sT = &lds[b][0];
    bf16x8 ah[4], al[4], bh[4], bl[4];
#pragma unroll
    for (int i = 0; i < 4; i++) {
      ah[i] = *reinterpret_cast<const bf16x8*>(sT + oah[i]);
      al[i] = *reinterpret_cast<const bf16x8*>(sT + oal[i]);
      bh[i] = *reinterpret_cast<const bf16x8*>(sT + obh[i]);
      bl[i] = *reinterpret_cast<const bf16x8*>(sT + obl[i]);
    }
    // My reads returned; block-wide barrier so no wave refills buf b early.
    asm volatile("s_waitcnt lgkmcnt(0)" ::: "memory");
    __builtin_amdgcn_sched_barrier(0);
    __builtin_amdgcn_s_barrier();
    if (t + 2 < nt) stage(b);  // refill buf b with tile t+2 (in flight across barriers)

    __builtin_amdgcn_s_setprio(1);
#pragma unroll
    for (int mi = 0; mi < 4; mi++)
#pragma unroll
      for (int ni = 0; ni < 4; ni++) {
        acc[mi][ni] = __builtin_amdgcn_mfma_f32_16x16x32_bf16(ah[mi], bh[ni], acc[mi][ni], 0, 0, 0);
        acc[mi][ni] = __builtin_amdgcn_mfma_f32_16x16x32_bf16(al[mi], bh[ni], acc[mi][ni], 0, 0, 0);
        acc[mi][ni] = __builtin_amdgcn_mfma_f32_16x16x32_bf16(ah[mi], bl[ni], acc[mi][ni], 0, 0, 0);
      }
    __builtin_amdgcn_s_setprio(0);
    __builtin_amdgcn_sched_barrier(0);

    // Counted wait: tile t+1's 8 loads must be done; tile t+2's 8 stay in flight.
    if (t + 2 < nt) {
      asm volatile("s_waitcnt vmcnt(8)" ::: "memory");
    } else if (t + 1 < nt) {
      asm volatile("s_waitcnt vmcnt(0)" ::: "memory");
    }
    __builtin_amdgcn_sched_barrier(0);
    if (t + 1 < nt) __builtin_amdgcn_s_barrier();
  }

  // epilogue: D row = fs*4+j, col = fr (m89-verified layout)
#pragma unroll
  for (int mi = 0; mi < 4; mi++) {
    int grow = m0 + wr * 64 + mi * 16 + fs * 4;
#pragma unroll
    for (int ni = 0; ni < 4; ni++) {
      int gcol = n0 + wc * 64 + ni * 16 + fr;
      float bv = bias[gcol];
      if (mode == 0) {
#pragma unroll
        for (int j = 0; j < 4; j++)
          C[(size_t)(grow + j) * N + gcol] = acc[mi][ni][j] + bv;
      } else {
#pragma unroll
        for (int j = 0; j < 4; j++) {
          size_t idx = (size_t)(grow + j) * N + gcol;
          float z = 1.f / (1.f + expf(-zbuf[idx]));  // zbuf aliases C: read-before-write, same thread
          float r = 1.f / (1.f + expf(-(acc[mi][ni][j] + bv)));
          float n = tanhf(xnbuf[idx] + r * hnbuf[idx]);
          C[idx] = (1.f - z) * n + z * hbuf[idx];
        }
      }
    }
  }
}

// ---- LayerNorm over new_h rows, emit hi/lo bf16 for the readout GEMM ----
__global__ __launch_bounds__(256) void ln_split(const float* __restrict__ src,
                                                const float* __restrict__ scale,
                                                const float* __restrict__ bias,
                                                u16* __restrict__ lhi, u16* __restrict__ llo) {
  int row = blockIdx.x, t = threadIdx.x;
  float4 vv = reinterpret_cast<const float4*>(src + (size_t)row * H_)[t];
  float v[4] = {vv.x, vv.y, vv.z, vv.w};
  float s = 0.f, s2 = 0.f;
#pragma unroll
  for (int i = 0; i < 4; i++) {
    s += v[i];
    s2 += v[i] * v[i];
  }
#pragma unroll
  for (int m = 32; m >= 1; m >>= 1) {
    s += __shfl_xor(s, m);
    s2 += __shfl_xor(s2, m);
  }
  __shared__ float red[8];
  int lane = t & 63, wv = t >> 6;
  if (lane == 0) {
    red[wv] = s;
    red[4 + wv] = s2;
  }
  __syncthreads();
  s = red[0] + red[1] + red[2] + red[3];
  s2 = red[4] + red[5] + red[6] + red[7];
  float mu = s * (1.f / H_);
  float var = s2 * (1.f / H_) - mu * mu;
  float inv = rsqrtf(var + 1e-6f);
  float4 sc = reinterpret_cast<const float4*>(scale)[t];
  float4 bi = reinterpret_cast<const float4*>(bias)[t];
  float scv[4] = {sc.x, sc.y, sc.z, sc.w};
  float biv[4] = {bi.x, bi.y, bi.z, bi.w};
  u16 hh[4], ll[4];
#pragma unroll
  for (int i = 0; i < 4; i++) {
    float y = (v[i] - mu) * inv * scv[i] + biv[i];
    hh[i] = f2bf(y);
    ll[i] = f2bf(y - bf2f(hh[i]));
  }
  ushort4 h4 = {hh[0], hh[1], hh[2], hh[3]};
  ushort4 l4 = {ll[0], ll[1], ll[2], ll[3]};
  reinterpret_cast<ushort4*>(lhi)[(size_t)row * 256 + t] = h4;
  reinterpret_cast<ushort4*>(llo)[(size_t)row * 256 + t] = l4;
}

extern "C" void kernel_launch(void* const* d_in, const int* in_sizes, int n_in,
                              void* d_out, int out_size, void* d_ws, size_t ws_size,
                              hipStream_t stream) {
  const float* x = (const float*)d_in[0];
  const float* h = (const float*)d_in[1];
  const float* Wir = (const float*)d_in[2];
  const float* bir = (const float*)d_in[3];
  const float* Wiz = (const float*)d_in[4];
  const float* biz = (const float*)d_in[5];
  const float* Win = (const float*)d_in[6];
  const float* bin_ = (const float*)d_in[7];
  const float* Whr = (const float*)d_in[8];
  const float* Whz = (const float*)d_in[9];
  const float* Whn = (const float*)d_in[10];
  const float* bhn = (const float*)d_in[11];
  const float* ln_scale = (const float*)d_in[12];
  const float* ln_bias = (const float*)d_in[13];
  const float* Wout = (const float*)d_in[14];
  const float* bout = (const float*)d_in[15];

  float* out_h = (float*)d_out;                    // [B][H] new_h (scratch: z-preact first)
  float* out_o = (float*)d_out + (size_t)B_ * H_;  // [B][O] out (scratch: xn-preact first)

  char* ws = (char*)d_ws;
  size_t off = 0;
  auto alloc = [&](size_t bytes) {
    void* p = ws + off;
    off += (bytes + 255) & ~(size_t)255;
    return p;
  };
  u16* xh_hi = (u16*)alloc((size_t)B_ * K2 * 2);    // 32 MB  [B][x|h]
  u16* xh_lo = (u16*)alloc((size_t)B_ * K2 * 2);    // 32 MB
  u16* WrT_hi = (u16*)alloc((size_t)H_ * K2 * 2);   // 4 MB   [H][Wir;Whr]^T
  u16* WrT_lo = (u16*)alloc((size_t)H_ * K2 * 2);
  u16* WzT_hi = (u16*)alloc((size_t)H_ * K2 * 2);
  u16* WzT_lo = (u16*)alloc((size_t)H_ * K2 * 2);
  u16* WinT_hi = (u16*)alloc((size_t)H_ * H_ * 2);  // 2 MB
  u16* WinT_lo = (u16*)alloc((size_t)H_ * H_ * 2);
  u16* WhnT_hi = (u16*)alloc((size_t)H_ * H_ * 2);
  u16* WhnT_lo = (u16*)alloc((size_t)H_ * H_ * 2);
  u16* WoT_hi = (u16*)alloc((size_t)H_ * H_ * 2);
  u16* WoT_lo = (u16*)alloc((size_t)H_ * H_ * 2);
  float* HN = (float*)alloc((size_t)B_ * H_ * 4);   // 32 MB  hn-preact
  // LN hi/lo ALIAS the xh buffers: xh is dead after the 4th (r) GEMM, and
  // ln_split runs after it on the same stream. Saves 32 MB -> total ~124 MB.
  u16* ln_hi = xh_hi;
  u16* ln_lo = xh_lo;

  split_hl<<<2048, 256, 0, stream>>>(x, xh_hi, xh_lo, 0);
  split_hl<<<2048, 256, 0, stream>>>(h, xh_hi, xh_lo, 256);

  dim3 tb(32, 8), tg(H_ / 32, H_ / 32);
  transpose_split<<<tg, tb, 0, stream>>>(Wir, WrT_hi, WrT_lo, H_, H_, K2, 0);
  transpose_split<<<tg, tb, 0, stream>>>(Whr, WrT_hi, WrT_lo, H_, H_, K2, 1024);
  transpose_split<<<tg, tb, 0, stream>>>(Wiz, WzT_hi, WzT_lo, H_, H_, K2, 0);
  transpose_split<<<tg, tb, 0, stream>>>(Whz, WzT_hi, WzT_lo, H_, H_, K2, 1024);
  transpose_split<<<tg, tb, 0, stream>>>(Win, WinT_hi, WinT_lo, H_, H_, H_, 0);
  transpose_split<<<tg, tb, 0, stream>>>(Whn, WhnT_hi, WhnT_lo, H_, H_, H_, 0);
  transpose_split<<<tg, tb, 0, stream>>>(Wout, WoT_hi, WoT_lo, H_, H_, H_, 0);

  dim3 gg(H_ / BN, B_ / BM);  // (8, 64) = 512 blocks, %8 == 0 for T1 swizzle
  // z-preact -> out_h
  gemm3<<<gg, 256, 0, stream>>>(xh_hi, xh_lo, K2, WzT_hi, WzT_lo, biz, out_h, H_, K2, 0,
                                nullptr, nullptr, nullptr, nullptr);
  // xn-preact -> out_o
  gemm3<<<gg, 256, 0, stream>>>(xh_hi, xh_lo, K2, WinT_hi, WinT_lo, bin_, out_o, H_, H_, 0,
                                nullptr, nullptr, nullptr, nullptr);
  // hn-preact -> HN
  gemm3<<<gg, 256, 0, stream>>>(xh_hi + H_, xh_lo + H_, K2, WhnT_hi, WhnT_lo, bhn, HN, H_, H_, 0,
                                nullptr, nullptr, nullptr, nullptr);
  // r-GEMM + fused gates: new_h -> out_h (in-place over z-preact)
  gemm3<<<gg, 256, 0, stream>>>(xh_hi, xh_lo, K2, WrT_hi, WrT_lo, bir, out_h, H_, K2, 1,
                                out_h, out_o, HN, h);
  // LayerNorm -> bf16 hi/lo (writes into dead xh region)
  ln_split<<<B_, 256, 0, stream>>>(out_h, ln_scale, ln_bias, ln_hi, ln_lo);
  // readout -> out_o (overwrites consumed xn-preact)
  gemm3<<<gg, 256, 0, stream>>>(ln_hi, ln_lo, H_, WoT_hi, WoT_lo, bout, out_o, H_, H_, 0,
                                nullptr, nullptr, nullptr, nullptr);
}

// Round 6
// 433.886 us; speedup vs baseline: 1.3559x; 1.3559x over previous
//
#include <hip/hip_runtime.h>
#include <math.h>

#define B_ 8192
#define H_ 1024
#define K2 2048

typedef __attribute__((ext_vector_type(8))) short bf16x8;
typedef __attribute__((ext_vector_type(4))) float f32x4;
typedef unsigned short u16;

__device__ __forceinline__ u16 f2bf(float f) {
  unsigned u = __float_as_uint(f);
  u += 0x7fffu + ((u >> 16) & 1u);  // round-to-nearest-even
  return (u16)(u >> 16);
}
__device__ __forceinline__ float bf2f(u16 s) { return __uint_as_float(((unsigned)s) << 16); }

// ---- split fp32 [B][1024] into hi/lo bf16 written into [B][2048] at column offset ----
__global__ __launch_bounds__(256) void split_hl(const float* __restrict__ src,
                                                u16* __restrict__ hi, u16* __restrict__ lo,
                                                int col04) {
  const int n4 = B_ * H_ / 4;
  int i = blockIdx.x * blockDim.x + threadIdx.x;
  int stride = gridDim.x * blockDim.x;
  for (; i < n4; i += stride) {
    float4 v = reinterpret_cast<const float4*>(src)[i];
    int row = i >> 8;  // 256 float4 per source row
    int c4 = i & 255;
    float c[4] = {v.x, v.y, v.z, v.w};
    u16 hh[4], ll[4];
#pragma unroll
    for (int j = 0; j < 4; j++) {
      hh[j] = f2bf(c[j]);
      ll[j] = f2bf(c[j] - bf2f(hh[j]));
    }
    ushort4 h4 = {hh[0], hh[1], hh[2], hh[3]};
    ushort4 l4 = {ll[0], ll[1], ll[2], ll[3]};
    size_t o4 = (size_t)row * (K2 / 4) + col04 + c4;
    reinterpret_cast<ushort4*>(hi)[o4] = h4;
    reinterpret_cast<ushort4*>(lo)[o4] = l4;
  }
}

// ---- W[K][N] -> T[N][ldo] (K-major), hi bf16 only (weights: single plane) ----
__global__ __launch_bounds__(256) void transpose_hi(const float* __restrict__ W,
                                                    u16* __restrict__ Thi,
                                                    int K, int N, int ldo, int koff) {
  __shared__ float tile[32][33];
  int bx = blockIdx.x * 32;  // N offset
  int by = blockIdx.y * 32;  // K offset
  int tx = threadIdx.x, ty = threadIdx.y;  // 32 x 8
#pragma unroll
  for (int i = 0; i < 4; i++)
    tile[ty + i * 8][tx] = W[(size_t)(by + ty + i * 8) * N + bx + tx];
  __syncthreads();
#pragma unroll
  for (int i = 0; i < 4; i++) {
    float v = tile[tx][ty + i * 8];  // = W[by+tx][bx+ty+i*8]
    size_t o = (size_t)(bx + ty + i * 8) * ldo + koff + by + tx;
    Thi[o] = f2bf(v);
  }
}

// ---- bf16x2 MFMA GEMM: C = (Ahi+Alo)[M][K](lda) * (Bhi[N][K])^T + bias[N] ----
// Terms kept: Ah*Bh + Al*Bh (activation split; weight lo-bits dropped -- adds
// ~2e-3 abs error to preacts, well under the reference-dominated 1.6e-2 absmax).
// Schedule: EXACT round-4 loop (compiler-managed waits; proven 0-conflict layout).
// mode 0: plain.  mode 1: fused GRU gate epilogue (acc is r-preact w/o bias).
#define BM 128
#define BN 128
#define BK 64

__device__ __forceinline__ void gload16(const void* g, void* l) {
  __builtin_amdgcn_global_load_lds((const __attribute__((address_space(1))) unsigned int*)g,
                                   (__attribute__((address_space(3))) unsigned int*)l,
                                   16, 0, 0);
}

__global__ __launch_bounds__(256, 3) void gemm3(const u16* __restrict__ Ahi,
                                                const u16* __restrict__ Alo, int lda,
                                                const u16* __restrict__ Bhi,
                                                const float* __restrict__ bias, float* C,
                                                int N, int K, int mode,
                                                const float* zbuf, const float* xnbuf,
                                                const float* hnbuf, const float* hbuf) {
  __shared__ u16 lds[3 * BM * BK];  // 48 KiB: Ahi, Alo, Bhi -> 3 blocks/CU
  u16* sAh = lds;
  u16* sAl = lds + BM * BK;
  u16* sBh = lds + 2 * BM * BK;

  const int tid = threadIdx.x;
  const int lane = tid & 63;
  const int wv = tid >> 6;
  const int wr = wv >> 1, wc = wv & 1;  // 2x2 waves, 64x64 tile each
  const int fr = lane & 15;
  const int fs = lane >> 4;

  // T1: bijective XCD chunk swizzle (nwg = 512, %8 == 0).
  const int lin = blockIdx.y * gridDim.x + blockIdx.x;
  const int cpx = (gridDim.x * gridDim.y) >> 3;
  const int nlin = (lin & 7) * cpx + (lin >> 3);
  const int m0 = (nlin / gridDim.x) * BM;
  const int n0 = (nlin % gridDim.x) * BN;

  f32x4 acc[4][4] = {};

  for (int k0 = 0; k0 < K; k0 += BK) {
    // Pre-swizzled GLOBAL source (rule #21): LDS slot s of row r holds logical
    // k-segment (s ^ (r&7)); linear gload_lds dest; read side applies same XOR.
    // This exact geometry measured SQ_LDS_BANK_CONFLICT == 0 (round 4).
#pragma unroll
    for (int q = 0; q < 4; q++) {
      int idx = q * 256 + tid;  // 16B-slot 0..1023
      int row = idx >> 3;
      int ls = (idx & 7) ^ (row & 7);  // logical 8-elem segment for this slot
      size_t ga = (size_t)(m0 + row) * lda + k0 + ls * 8;
      size_t gb = (size_t)(n0 + row) * K + k0 + ls * 8;
      gload16(Ahi + ga, sAh + (size_t)idx * 8);
      gload16(Alo + ga, sAl + (size_t)idx * 8);
      gload16(Bhi + gb, sBh + (size_t)idx * 8);
    }
    __syncthreads();

#pragma unroll
    for (int kh = 0; kh < 2; kh++) {
      bf16x8 ah[4], al[4], bh[4];
#pragma unroll
      for (int i = 0; i < 4; i++) {
        int ar = wr * 64 + i * 16 + fr;
        int ao = ar * 64 + (((kh * 4 + fs) ^ (ar & 7)) << 3);
        ah[i] = *reinterpret_cast<const bf16x8*>(sAh + ao);
        al[i] = *reinterpret_cast<const bf16x8*>(sAl + ao);
        int br = wc * 64 + i * 16 + fr;
        int bo = br * 64 + (((kh * 4 + fs) ^ (br & 7)) << 3);
        bh[i] = *reinterpret_cast<const bf16x8*>(sBh + bo);
      }
#pragma unroll
      for (int mi = 0; mi < 4; mi++)
#pragma unroll
        for (int ni = 0; ni < 4; ni++) {
          acc[mi][ni] = __builtin_amdgcn_mfma_f32_16x16x32_bf16(ah[mi], bh[ni], acc[mi][ni], 0, 0, 0);
          acc[mi][ni] = __builtin_amdgcn_mfma_f32_16x16x32_bf16(al[mi], bh[ni], acc[mi][ni], 0, 0, 0);
        }
    }
    __syncthreads();
  }

  // epilogue: D row = fs*4+j, col = fr (m89-verified layout)
#pragma unroll
  for (int mi = 0; mi < 4; mi++) {
    int grow = m0 + wr * 64 + mi * 16 + fs * 4;
#pragma unroll
    for (int ni = 0; ni < 4; ni++) {
      int gcol = n0 + wc * 64 + ni * 16 + fr;
      float bv = bias[gcol];
      if (mode == 0) {
#pragma unroll
        for (int j = 0; j < 4; j++)
          C[(size_t)(grow + j) * N + gcol] = acc[mi][ni][j] + bv;
      } else {
#pragma unroll
        for (int j = 0; j < 4; j++) {
          size_t idx = (size_t)(grow + j) * N + gcol;
          float z = 1.f / (1.f + expf(-zbuf[idx]));  // zbuf aliases C: read-before-write, same thread
          float r = 1.f / (1.f + expf(-(acc[mi][ni][j] + bv)));
          float n = tanhf(xnbuf[idx] + r * hnbuf[idx]);
          C[idx] = (1.f - z) * n + z * hbuf[idx];
        }
      }
    }
  }
}

// ---- LayerNorm over new_h rows, emit hi/lo bf16 for the readout GEMM ----
__global__ __launch_bounds__(256) void ln_split(const float* __restrict__ src,
                                                const float* __restrict__ scale,
                                                const float* __restrict__ bias,
                                                u16* __restrict__ lhi, u16* __restrict__ llo) {
  int row = blockIdx.x, t = threadIdx.x;
  float4 vv = reinterpret_cast<const float4*>(src + (size_t)row * H_)[t];
  float v[4] = {vv.x, vv.y, vv.z, vv.w};
  float s = 0.f, s2 = 0.f;
#pragma unroll
  for (int i = 0; i < 4; i++) {
    s += v[i];
    s2 += v[i] * v[i];
  }
#pragma unroll
  for (int m = 32; m >= 1; m >>= 1) {
    s += __shfl_xor(s, m);
    s2 += __shfl_xor(s2, m);
  }
  __shared__ float red[8];
  int lane = t & 63, wv = t >> 6;
  if (lane == 0) {
    red[wv] = s;
    red[4 + wv] = s2;
  }
  __syncthreads();
  s = red[0] + red[1] + red[2] + red[3];
  s2 = red[4] + red[5] + red[6] + red[7];
  float mu = s * (1.f / H_);
  float var = s2 * (1.f / H_) - mu * mu;
  float inv = rsqrtf(var + 1e-6f);
  float4 sc = reinterpret_cast<const float4*>(scale)[t];
  float4 bi = reinterpret_cast<const float4*>(bias)[t];
  float scv[4] = {sc.x, sc.y, sc.z, sc.w};
  float biv[4] = {bi.x, bi.y, bi.z, bi.w};
  u16 hh[4], ll[4];
#pragma unroll
  for (int i = 0; i < 4; i++) {
    float y = (v[i] - mu) * inv * scv[i] + biv[i];
    hh[i] = f2bf(y);
    ll[i] = f2bf(y - bf2f(hh[i]));
  }
  ushort4 h4 = {hh[0], hh[1], hh[2], hh[3]};
  ushort4 l4 = {ll[0], ll[1], ll[2], ll[3]};
  reinterpret_cast<ushort4*>(lhi)[(size_t)row * 256 + t] = h4;
  reinterpret_cast<ushort4*>(llo)[(size_t)row * 256 + t] = l4;
}

extern "C" void kernel_launch(void* const* d_in, const int* in_sizes, int n_in,
                              void* d_out, int out_size, void* d_ws, size_t ws_size,
                              hipStream_t stream) {
  const float* x = (const float*)d_in[0];
  const float* h = (const float*)d_in[1];
  const float* Wir = (const float*)d_in[2];
  const float* bir = (const float*)d_in[3];
  const float* Wiz = (const float*)d_in[4];
  const float* biz = (const float*)d_in[5];
  const float* Win = (const float*)d_in[6];
  const float* bin_ = (const float*)d_in[7];
  const float* Whr = (const float*)d_in[8];
  const float* Whz = (const float*)d_in[9];
  const float* Whn = (const float*)d_in[10];
  const float* bhn = (const float*)d_in[11];
  const float* ln_scale = (const float*)d_in[12];
  const float* ln_bias = (const float*)d_in[13];
  const float* Wout = (const float*)d_in[14];
  const float* bout = (const float*)d_in[15];

  float* out_h = (float*)d_out;                    // [B][H] new_h (scratch: z-preact first)
  float* out_o = (float*)d_out + (size_t)B_ * H_;  // [B][O] out (scratch: xn-preact first)

  char* ws = (char*)d_ws;
  size_t off = 0;
  auto alloc = [&](size_t bytes) {
    void* p = ws + off;
    off += (bytes + 255) & ~(size_t)255;
    return p;
  };
  u16* xh_hi = (u16*)alloc((size_t)B_ * K2 * 2);    // 32 MB  [B][x|h]
  u16* xh_lo = (u16*)alloc((size_t)B_ * K2 * 2);    // 32 MB
  u16* WrT_hi = (u16*)alloc((size_t)H_ * K2 * 2);   // 4 MB   [H][Wir;Whr]^T
  u16* WzT_hi = (u16*)alloc((size_t)H_ * K2 * 2);   // 4 MB
  u16* WinT_hi = (u16*)alloc((size_t)H_ * H_ * 2);  // 2 MB
  u16* WhnT_hi = (u16*)alloc((size_t)H_ * H_ * 2);
  u16* WoT_hi = (u16*)alloc((size_t)H_ * H_ * 2);
  float* HN = (float*)alloc((size_t)B_ * H_ * 4);   // 32 MB  hn-preact
  // LN hi/lo ALIAS the xh buffers: xh is dead after the 4th (r) GEMM, and
  // ln_split runs after it on the same stream. Total ws ~110 MB.
  u16* ln_hi = xh_hi;
  u16* ln_lo = xh_lo;

  split_hl<<<2048, 256, 0, stream>>>(x, xh_hi, xh_lo, 0);
  split_hl<<<2048, 256, 0, stream>>>(h, xh_hi, xh_lo, 256);

  dim3 tb(32, 8), tg(H_ / 32, H_ / 32);
  transpose_hi<<<tg, tb, 0, stream>>>(Wir, WrT_hi, H_, H_, K2, 0);
  transpose_hi<<<tg, tb, 0, stream>>>(Whr, WrT_hi, H_, H_, K2, 1024);
  transpose_hi<<<tg, tb, 0, stream>>>(Wiz, WzT_hi, H_, H_, K2, 0);
  transpose_hi<<<tg, tb, 0, stream>>>(Whz, WzT_hi, H_, H_, K2, 1024);
  transpose_hi<<<tg, tb, 0, stream>>>(Win, WinT_hi, H_, H_, H_, 0);
  transpose_hi<<<tg, tb, 0, stream>>>(Whn, WhnT_hi, H_, H_, H_, 0);
  transpose_hi<<<tg, tb, 0, stream>>>(Wout, WoT_hi, H_, H_, H_, 0);

  dim3 gg(H_ / BN, B_ / BM);  // (8, 64) = 512 blocks, %8 == 0 for T1 swizzle
  // z-preact -> out_h
  gemm3<<<gg, 256, 0, stream>>>(xh_hi, xh_lo, K2, WzT_hi, biz, out_h, H_, K2, 0,
                                nullptr, nullptr, nullptr, nullptr);
  // xn-preact -> out_o
  gemm3<<<gg, 256, 0, stream>>>(xh_hi, xh_lo, K2, WinT_hi, bin_, out_o, H_, H_, 0,
                                nullptr, nullptr, nullptr, nullptr);
  // hn-preact -> HN
  gemm3<<<gg, 256, 0, stream>>>(xh_hi + H_, xh_lo + H_, K2, WhnT_hi, bhn, HN, H_, H_, 0,
                                nullptr, nullptr, nullptr, nullptr);
  // r-GEMM + fused gates: new_h -> out_h (in-place over z-preact)
  gemm3<<<gg, 256, 0, stream>>>(xh_hi, xh_lo, K2, WrT_hi, bir, out_h, H_, K2, 1,
                                out_h, out_o, HN, h);
  // LayerNorm -> bf16 hi/lo (writes into dead xh region)
  ln_split<<<B_, 256, 0, stream>>>(out_h, ln_scale, ln_bias, ln_hi, ln_lo);
  // readout -> out_o (overwrites consumed xn-preact)
  gemm3<<<gg, 256, 0, stream>>>(ln_hi, ln_lo, H_, WoT_hi, bout, out_o, H_, H_, 0,
                                nullptr, nullptr, nullptr, nullptr);
}